// Round 3
// baseline (143.685 us; speedup 1.0000x reference)
//
#include <hip/hip_runtime.h>

#define CROPPX 4
#define H 504
#define W 504
#define IMG 512
#define NB 16
#define NCH 3
#define KS 11
#define RAD 5
#define TW 64               // output cols per block
#define STRIP (TW + 2*RAD)  // 74 input cols per block
#define RPS 18              // output rows per segment (28*18 = 504 exactly)
#define NSEG 28
#define NXT 8               // ceil(504/64): last tile has 56 valid cols
#define ROWS (RPS + 2*RAD)  // 28 input rows staged per block
#define CHUNK 7             // rows loaded per batch (28 = 4*7)

__global__ __launch_bounds__(64) void ssim_main(const float* __restrict__ img1,
                                                const float* __restrict__ img2,
                                                float* __restrict__ partial) {
    const int tid = threadIdx.x;
    const int gx0 = blockIdx.x * TW;   // first output col of tile
    const int y0  = blockIdx.y * RPS;  // first output row of segment
    const int b   = blockIdx.z;        // batch

    __shared__ float2 strip[ROWS][STRIP];  // (img1,img2) interleaved, 28x74x8 = 16.2 KB

    const float* p1 = img1 + (size_t)(b * NCH) * IMG * IMG + (size_t)CROPPX * IMG + CROPPX;
    const float* p2 = img2 + (size_t)(b * NCH) * IMG * IMG + (size_t)CROPPX * IMG + CROPPX;

    const int c0 = gx0 - RAD + tid;    // this lane's strip col (first 64)
    const int c1 = c0 + 64;            // second strip col (10 lanes)
    const bool lane2 = tid < (STRIP - 64);
    const bool c0ok = (unsigned)c0 < (unsigned)W;
    const bool c1ok = lane2 && ((unsigned)c1 < (unsigned)W);

    // ---- phase 1: bulk load 28 rows into LDS, high MLP (28 loads in flight/chunk)
    #pragma unroll
    for (int rc = 0; rc < ROWS / CHUNK; ++rc) {
        float a0[CHUNK], b0[CHUNK], a1[CHUNK], b1[CHUNK];
        #pragma unroll
        for (int j = 0; j < CHUNK; ++j) {
            const int r = y0 - RAD + rc * CHUNK + j;
            a0[j] = 0.f; b0[j] = 0.f; a1[j] = 0.f; b1[j] = 0.f;
            if ((unsigned)r < (unsigned)H) {
                const size_t ro = (size_t)r * IMG;
                if (c0ok) { a0[j] = p1[ro + c0]; b0[j] = p2[ro + c0]; }
                if (c1ok) { a1[j] = p1[ro + c1]; b1[j] = p2[ro + c1]; }
            }
        }
        #pragma unroll
        for (int j = 0; j < CHUNK; ++j) {
            const int r = rc * CHUNK + j;
            strip[r][tid] = make_float2(a0[j], b0[j]);
            if (lane2) strip[r][64 + tid] = make_float2(a1[j], b1[j]);
        }
    }
    __syncthreads();   // only barrier in the kernel; LDS is read-only afterwards

    // ---- phase 2: pure LDS+VALU sliding-window compute
    float r1[KS], r2[KS], r11[KS], r22[KS], r12[KS];
    #pragma unroll
    for (int j = 0; j < KS; ++j) { r1[j]=0.f; r2[j]=0.f; r11[j]=0.f; r22[j]=0.f; r12[j]=0.f; }

    float vs1 = 0.f, vs2 = 0.f, vs11 = 0.f, vs22 = 0.f, vs12 = 0.f;
    float ssum = 0.f;
    const float C1 = 6.5025f, C2 = 58.5225f;
    const float inv121 = 1.0f / 121.0f;
    const bool colValid = (gx0 + tid) < W;

    for (int base = 0; base < ROWS; base += KS) {   // base in {0,11,22}; base%11==0
        #pragma unroll
        for (int j = 0; j < KS; ++j) {
            const int iter = base + j;
            if (iter >= ROWS) break;

            // horizontal 11-tap sums for output col gx0+tid, row `iter`
            float h1 = 0.f, h2 = 0.f, h11 = 0.f, h22 = 0.f, h12 = 0.f;
            #pragma unroll
            for (int dx = 0; dx < KS; ++dx) {
                const float2 ab = strip[iter][tid + dx];
                h1 += ab.x;
                h2 += ab.y;
                h11 = fmaf(ab.x, ab.x, h11);
                h22 = fmaf(ab.y, ab.y, h22);
                h12 = fmaf(ab.x, ab.y, h12);
            }

            // vertical sliding window; ring slot == iter % 11 == j
            vs1  += h1  - r1[j];  r1[j]  = h1;
            vs2  += h2  - r2[j];  r2[j]  = h2;
            vs11 += h11 - r11[j]; r11[j] = h11;
            vs22 += h22 - r22[j]; r22[j] = h22;
            vs12 += h12 - r12[j]; r12[j] = h12;

            // window covers rows [iter-10, iter] => output row iter-5 of segment
            if (iter >= 2 * RAD && colValid) {
                const float mu1 = vs1 * inv121;
                const float mu2 = vs2 * inv121;
                const float mu1s = mu1 * mu1;
                const float mu2s = mu2 * mu2;
                const float m12  = mu1 * mu2;
                const float s1  = fmaf(vs11, inv121, -mu1s);
                const float s2  = fmaf(vs22, inv121, -mu2s);
                const float s12 = fmaf(vs12, inv121, -m12);
                const float num = (2.0f * m12 + C1) * (2.0f * s12 + C2);
                const float den = (mu1s + mu2s + C1) * (s1 + s2 + C2);
                ssum = fmaf(num, __builtin_amdgcn_rcpf(den), ssum);
            }
        }
    }

    // wave (64-lane) reduction of ssum
    for (int off = 32; off > 0; off >>= 1)
        ssum += __shfl_down(ssum, off);
    if (tid == 0) {
        const int bidx = (blockIdx.z * gridDim.y + blockIdx.y) * gridDim.x + blockIdx.x;
        partial[bidx] = ssum;
    }
}

__global__ __launch_bounds__(256) void ssim_final(const float* __restrict__ partial,
                                                  int n, float* __restrict__ out) {
    __shared__ double sh[256];
    double s = 0.0;
    for (int i = threadIdx.x; i < n; i += 256) s += (double)partial[i];
    sh[threadIdx.x] = s;
    __syncthreads();
    for (int stride = 128; stride > 0; stride >>= 1) {
        if (threadIdx.x < stride) sh[threadIdx.x] += sh[threadIdx.x + stride];
        __syncthreads();
    }
    if (threadIdx.x == 0)
        out[0] = (float)(sh[0] / ((double)NB * (double)H * (double)W));
}

extern "C" void kernel_launch(void* const* d_in, const int* in_sizes, int n_in,
                              void* d_out, int out_size, void* d_ws, size_t ws_size,
                              hipStream_t stream) {
    const float* img1 = (const float*)d_in[0];
    const float* img2 = (const float*)d_in[1];
    float* out = (float*)d_out;
    float* partial = (float*)d_ws;  // NXT*NSEG*NB floats = 14.3 KiB

    dim3 grid(NXT, NSEG, NB);
    ssim_main<<<grid, 64, 0, stream>>>(img1, img2, partial);
    ssim_final<<<1, 256, 0, stream>>>(partial, NXT * NSEG * NB, out);
}